// Round 2
// baseline (263.345 us; speedup 1.0000x reference)
//
#include <hip/hip_runtime.h>

#define HH 256
#define WW 704
#define DD 64
#define CC 3
#define BB 2
#define HWN (HH * WW)   // 180224, divisible by 64 and 256

static constexpr float INV2Z2 = 1.0f / (2.0f * 1e-3f * 1e-3f);  // 1/(2*zeta^2) = 5e5

// ---------------------------------------------------------------------------
// Affinity kernel: kaff[b,k,n] = ws * exp(-sum_c (uc[c,k,n]-color[c,n])^2 / (2 zeta^2))
// Zero padding: out-of-bounds neighbor value is 0 -> diff = -center (contributes center^2).
// ---------------------------------------------------------------------------
__global__ __launch_bounds__(256) void affinity_kernel(
    const float* __restrict__ color, const float* __restrict__ wsp,
    float* __restrict__ kaff)
{
    int n = blockIdx.x * 256 + threadIdx.x;
    int b = blockIdx.y;
    int h = n / WW, w = n - h * WW;
    float wsv = wsp[0];

    const float* cb = color + (size_t)b * CC * HWN + n;
    float c0 = cb[0], c1 = cb[HWN], c2 = cb[2 * HWN];
    bool hm = h > 0, hp = h < HH - 1, wm = w > 0, wp = w < WW - 1;

    float* kb = kaff + (size_t)b * 9 * HWN + n;
#pragma unroll
    for (int dh = -1; dh <= 1; ++dh) {
#pragma unroll
        for (int dw = -1; dw <= 1; ++dw) {
            int k = (dh + 1) * 3 + (dw + 1);
            bool valid = (dh < 0 ? hm : (dh > 0 ? hp : true)) &&
                         (dw < 0 ? wm : (dw > 0 ? wp : true));
            int off = valid ? (dh * WW + dw) : 0;
            float u0 = valid ? cb[off] : 0.f;
            float u1 = valid ? cb[HWN + off] : 0.f;
            float u2 = valid ? cb[2 * HWN + off] : 0.f;
            float d0 = u0 - c0, d1 = u1 - c1, d2 = u2 - c2;
            float ss = d0 * d0 + d1 * d1 + d2 * d2;
            kb[(size_t)k * HWN] = wsv * __expf(-ss * INV2Z2);
        }
    }
}

// ---------------------------------------------------------------------------
// Lane layout shared by softmax0 and crf_iter:
//   wave = 64 lanes = 16 pixels x 4 channel-groups.
//   lane: j = lane>>4 (channel group, owns e in [16j,16j+16)), pix = lane&15.
//   Loads/stores: for fixed i, each 16-lane group reads 64B contiguous. Cross-
//   lane combines via __shfl / __shfl_xor(16|32).
// ---------------------------------------------------------------------------

__global__ __launch_bounds__(256) void softmax0_kernel(
    const float* __restrict__ logits, float* __restrict__ q)
{
    const int t = threadIdx.x;
    const int lane = t & 63;
    const int j = lane >> 4;
    const int pix = lane & 15;
    const int wv = t >> 6;
    const int n = blockIdx.x * 64 + wv * 16 + pix;
    const int b = blockIdx.y;

    const float* lg = logits + ((size_t)b * DD + j * 16) * HWN + n;
    float v[16];
    float m = -3.0e38f;
#pragma unroll
    for (int i = 0; i < 16; ++i) {
        v[i] = lg[(size_t)i * HWN];
        m = fmaxf(m, v[i]);
    }
    m = fmaxf(m, __shfl_xor(m, 16));
    m = fmaxf(m, __shfl_xor(m, 32));
    float s = 0.f;
#pragma unroll
    for (int i = 0; i < 16; ++i) { float p = __expf(v[i] - m); v[i] = p; s += p; }
    s += __shfl_xor(s, 16);
    s += __shfl_xor(s, 32);
    float inv = 1.0f / s;
    float* qb = q + ((size_t)b * DD + j * 16) * HWN + n;
#pragma unroll
    for (int i = 0; i < 16; ++i) qb[(size_t)i * HWN] = v[i] * inv;
}

// ---------------------------------------------------------------------------
// One CRF iteration, 4 lanes per pixel (16 channels each):
//   t[e]     = sum_k kaff[k,n] * q[e, nbr_k(n)]        (ws folded into kaff)
//   q_hat[d] = sum_e |d-e| t[e] via prefix sums:
//              A[d]=sum_{e<=d} t, Bp[d]=sum_{e<=d} e*t, T=A[63], E=Bp[63]
//              q_hat[d] = 2(d*A[d]-Bp[d]) + E - d*T
//   q_out    = softmax_d(logits - q_hat)
// Cross-lane: 4-way exclusive prefix of (A,Bp) via __shfl; max/sum reductions
// via __shfl_xor(16|32). Border: zero invalid weights + clamp offsets.
// ---------------------------------------------------------------------------
__global__ __launch_bounds__(256) void crf_iter_kernel(
    const float* __restrict__ qin, const float* __restrict__ logits,
    const float* __restrict__ kaff, float* __restrict__ qout)
{
    const int t = threadIdx.x;
    const int lane = t & 63;
    const int j = lane >> 4;
    const int pix = lane & 15;
    const int wv = t >> 6;
    const int n = blockIdx.x * 64 + wv * 16 + pix;
    const int b = blockIdx.y;
    const int h = n / WW, w = n - h * WW;

    const float* kb = kaff + (size_t)b * 9 * HWN + n;
    float k0 = kb[0];
    float k1 = kb[1 * HWN];
    float k2 = kb[2 * HWN];
    float k3 = kb[3 * HWN];
    float k4 = kb[4 * HWN];
    float k5 = kb[5 * HWN];
    float k6 = kb[6 * HWN];
    float k7 = kb[7 * HWN];
    float k8 = kb[8 * HWN];

    bool hm = h > 0, hp = h < HH - 1, wm = w > 0, wp = w < WW - 1;
    if (!hm) { k0 = k1 = k2 = 0.f; }
    if (!hp) { k6 = k7 = k8 = 0.f; }
    if (!wm) { k0 = k3 = k6 = 0.f; }
    if (!wp) { k2 = k5 = k8 = 0.f; }
    int oN = hm ? -WW : 0, oS = hp ? WW : 0;
    int oW = wm ? -1 : 0,  oE = wp ? 1 : 0;

    const float* qp = qin + ((size_t)b * DD + j * 16) * HWN + n;

    float tv[16];
    float Aloc = 0.f, Bloc = 0.f;
#pragma unroll
    for (int i = 0; i < 16; ++i) {
        const float* qe = qp + (size_t)i * HWN;
        float tt = k0 * qe[oN + oW] + k1 * qe[oN] + k2 * qe[oN + oE]
                 + k3 * qe[oW]      + k4 * qe[0]  + k5 * qe[oE]
                 + k6 * qe[oS + oW] + k7 * qe[oS] + k8 * qe[oS + oE];
        tv[i] = tt;
        Aloc += tt;
        Bloc += (float)(j * 16 + i) * tt;
    }

    // 4-way exclusive prefix + totals across channel groups
    float A0 = __shfl(Aloc, pix),      A1 = __shfl(Aloc, pix + 16),
          A2 = __shfl(Aloc, pix + 32), A3 = __shfl(Aloc, pix + 48);
    float B0 = __shfl(Bloc, pix),      B1 = __shfl(Bloc, pix + 16),
          B2 = __shfl(Bloc, pix + 32), B3 = __shfl(Bloc, pix + 48);
    float T = A0 + A1 + A2 + A3;
    float E = B0 + B1 + B2 + B3;
    float Arun = 0.f, Brun = 0.f;
    if (j > 0) { Arun += A0; Brun += B0; }
    if (j > 1) { Arun += A1; Brun += B1; }
    if (j > 2) { Arun += A2; Brun += B2; }

    const float* lg = logits + ((size_t)b * DD + j * 16) * HWN + n;
    float m = -3.0e38f;
#pragma unroll
    for (int i = 0; i < 16; ++i) {
        float e = (float)(j * 16 + i);
        Arun += tv[i];
        Brun += e * tv[i];
        float vv = lg[(size_t)i * HWN] - (2.0f * (e * Arun - Brun) + E - e * T);
        tv[i] = vv;
        m = fmaxf(m, vv);
    }
    m = fmaxf(m, __shfl_xor(m, 16));
    m = fmaxf(m, __shfl_xor(m, 32));
    float s = 0.f;
#pragma unroll
    for (int i = 0; i < 16; ++i) { float p = __expf(tv[i] - m); tv[i] = p; s += p; }
    s += __shfl_xor(s, 16);
    s += __shfl_xor(s, 32);
    float inv = 1.0f / s;

    float* qo = qout + ((size_t)b * DD + j * 16) * HWN + n;
#pragma unroll
    for (int i = 0; i < 16; ++i) qo[(size_t)i * HWN] = tv[i] * inv;
}

// ---------------------------------------------------------------------------
extern "C" void kernel_launch(void* const* d_in, const int* in_sizes, int n_in,
                              void* d_out, int out_size, void* d_ws, size_t ws_size,
                              hipStream_t stream) {
    const float* color  = (const float*)d_in[0];
    // d_in[1] = feats: unused by the forward pass
    const float* logits = (const float*)d_in[2];
    const float* wsp    = (const float*)d_in[3];

    float* q_out = (float*)d_out;                       // q0, then final q
    float* kaff  = (float*)d_ws;                        // [B,9,HW]  ~13 MB
    float* q1    = (float*)d_ws + (size_t)BB * 9 * HWN; // [B,D,HW]  ~92 MB

    dim3 gridA(HWN / 256, BB);
    dim3 gridQ(HWN / 64, BB);
    affinity_kernel<<<gridA, 256, 0, stream>>>(color, wsp, kaff);
    softmax0_kernel<<<gridQ, 256, 0, stream>>>(logits, q_out);
    crf_iter_kernel<<<gridQ, 256, 0, stream>>>(q_out, logits, kaff, q1);
    crf_iter_kernel<<<gridQ, 256, 0, stream>>>(q1, logits, kaff, q_out);
}

// Round 3
// 183.177 us; speedup vs baseline: 1.4377x; 1.4377x over previous
//
#include <hip/hip_runtime.h>

#define HH 256
#define WW 704
#define DD 64
#define CC 3
#define BB 2
#define HWN (HH * WW)   // 180224; WW%32==0 so 32-px groups never straddle rows

static constexpr float INV2Z2 = 1.0f / (2.0f * 1e-3f * 1e-3f);  // 1/(2*zeta^2)

// ---------------------------------------------------------------------------
// Affinity: kaff[b,k,n] = ws * exp(-sum_c (uc-c)^2/(2 zeta^2)). Border tap
// values are irrelevant (weights are masked in crf_iter), computed anyway.
// ---------------------------------------------------------------------------
__global__ __launch_bounds__(256) void affinity_kernel(
    const float* __restrict__ color, const float* __restrict__ wsp,
    float* __restrict__ kaff)
{
    int n = blockIdx.x * 256 + threadIdx.x;
    int b = blockIdx.y;
    int h = n / WW, w = n - h * WW;
    float wsv = wsp[0];

    const float* cb = color + (size_t)b * CC * HWN + n;
    float c0 = cb[0], c1 = cb[HWN], c2 = cb[2 * HWN];
    bool hm = h > 0, hp = h < HH - 1, wm = w > 0, wp = w < WW - 1;

    float* kb = kaff + (size_t)b * 9 * HWN + n;
#pragma unroll
    for (int dh = -1; dh <= 1; ++dh) {
#pragma unroll
        for (int dw = -1; dw <= 1; ++dw) {
            int k = (dh + 1) * 3 + (dw + 1);
            bool valid = (dh < 0 ? hm : (dh > 0 ? hp : true)) &&
                         (dw < 0 ? wm : (dw > 0 ? wp : true));
            int off = valid ? (dh * WW + dw) : 0;
            float u0 = valid ? cb[off] : 0.f;
            float u1 = valid ? cb[HWN + off] : 0.f;
            float u2 = valid ? cb[2 * HWN + off] : 0.f;
            float d0 = u0 - c0, d1 = u1 - c1, d2 = u2 - c2;
            float ss = d0 * d0 + d1 * d1 + d2 * d2;
            kb[(size_t)k * HWN] = wsv * __expf(-ss * INV2Z2);
        }
    }
}

// ---------------------------------------------------------------------------
// Lane layout for softmax0 / crf_iter:
//   wave = 64 lanes = 8 pixel-groups (4 px each, float4) x 8 channel-groups.
//   pg = lane & 7 (contiguous lanes -> contiguous 128B), cg = lane >> 3.
//   Thread owns 4 px x 8 channels [8*cg, 8*cg+8).
// ---------------------------------------------------------------------------

// inclusive scan over the 8 channel-groups (lanes same pg, stride 8)
__device__ __forceinline__ void scan8(float& incl, float& excl, float& tot,
                                      int cg, int pg) {
    float own = incl, v;
    v = __shfl_up(incl, 8);  incl += (cg >= 1) ? v : 0.f;
    v = __shfl_up(incl, 16); incl += (cg >= 2) ? v : 0.f;
    v = __shfl_up(incl, 32); incl += (cg >= 4) ? v : 0.f;
    excl = incl - own;
    tot = __shfl(incl, 56 + pg);
}

__global__ __launch_bounds__(256) void softmax0_kernel(
    const float* __restrict__ logits, float* __restrict__ q)
{
    const int t = threadIdx.x, lane = t & 63, wv = t >> 6;
    const int pg = lane & 7, cg = lane >> 3;
    const int n0 = blockIdx.x * 128 + wv * 32 + pg * 4;
    const int b = blockIdx.y;

    const float* lg = logits + ((size_t)(b * DD + cg * 8)) * HWN + n0;
    float4 u[8];
    float4 S = make_float4(0.f, 0.f, 0.f, 0.f);
#pragma unroll
    for (int i = 0; i < 8; ++i) {
        float4 v = *(const float4*)(lg + (size_t)i * HWN);
        u[i].x = __expf(v.x); u[i].y = __expf(v.y);
        u[i].z = __expf(v.z); u[i].w = __expf(v.w);
        S.x += u[i].x; S.y += u[i].y; S.z += u[i].z; S.w += u[i].w;
    }
#pragma unroll
    for (int o = 8; o <= 32; o <<= 1) {
        S.x += __shfl_xor(S.x, o); S.y += __shfl_xor(S.y, o);
        S.z += __shfl_xor(S.z, o); S.w += __shfl_xor(S.w, o);
    }
    float4 inv = make_float4(1.f / S.x, 1.f / S.y, 1.f / S.z, 1.f / S.w);
    float* qb = q + ((size_t)(b * DD + cg * 8)) * HWN + n0;
#pragma unroll
    for (int i = 0; i < 8; ++i) {
        float4 o;
        o.x = u[i].x * inv.x; o.y = u[i].y * inv.y;
        o.z = u[i].z * inv.z; o.w = u[i].w * inv.w;
        *(float4*)(qb + (size_t)i * HWN) = o;
    }
}

// ---------------------------------------------------------------------------
// One CRF iteration (see round-1 prefix-sum derivation):
//   t[e]     = sum_k kaff[k,n] * q[e, nbr_k(n)]
//   q_hat[d] = 2(d*A[d]-Bp[d]) + E - d*T   (A,Bp inclusive prefixes of t, e*t)
//   q_out    = softmax_d(logits - q_hat)   (no max-sub: |v| <= ~22, fp32 safe)
// float4 spatial vectorization; border via weight masks + clamped addresses.
// Slab XCD swizzle: (bid&7)*176 + bid>>3 keeps spatially-adjacent blocks on
// one XCD so stencil halo lines / row+-1 reuse hit that XCD's L2.
// ---------------------------------------------------------------------------
__global__ __launch_bounds__(256) void crf_iter_kernel(
    const float* __restrict__ qin, const float* __restrict__ logits,
    const float* __restrict__ kaff, float* __restrict__ qout)
{
    const int t = threadIdx.x, lane = t & 63, wv = t >> 6;
    const int pg = lane & 7, cg = lane >> 3;
    const int bid = blockIdx.x;                       // 0..1407
    const int pb = (bid & 7) * (HWN / 128 / 8) + (bid >> 3);
    const int n0 = pb * 128 + wv * 32 + pg * 4;
    const int b = blockIdx.y;
    const int h = n0 / WW, w0 = n0 - h * WW;          // w0 multiple of 4

    // 9 affinity weight vectors for these 4 px
    const float* kb = kaff + (size_t)b * 9 * HWN + n0;
    float4 k0 = *(const float4*)(kb + 0 * HWN);
    float4 k1 = *(const float4*)(kb + 1 * HWN);
    float4 k2 = *(const float4*)(kb + 2 * HWN);
    float4 k3 = *(const float4*)(kb + 3 * HWN);
    float4 k4 = *(const float4*)(kb + 4 * HWN);
    float4 k5 = *(const float4*)(kb + 5 * HWN);
    float4 k6 = *(const float4*)(kb + 6 * HWN);
    float4 k7 = *(const float4*)(kb + 7 * HWN);
    float4 k8 = *(const float4*)(kb + 8 * HWN);

    const bool hm = h > 0, hp = h < HH - 1;
    const float mt = hm ? 1.f : 0.f, mb = hp ? 1.f : 0.f;
    const float ml = (w0 > 0) ? 1.f : 0.f;            // only px .x can be w==0
    const float mr = (w0 < WW - 4) ? 1.f : 0.f;       // only px .w can be w==WW-1
    k0.x *= mt; k0.y *= mt; k0.z *= mt; k0.w *= mt;
    k1.x *= mt; k1.y *= mt; k1.z *= mt; k1.w *= mt;
    k2.x *= mt; k2.y *= mt; k2.z *= mt; k2.w *= mt;
    k6.x *= mb; k6.y *= mb; k6.z *= mb; k6.w *= mb;
    k7.x *= mb; k7.y *= mb; k7.z *= mb; k7.w *= mb;
    k8.x *= mb; k8.y *= mb; k8.z *= mb; k8.w *= mb;
    k0.x *= ml; k3.x *= ml; k6.x *= ml;
    k2.w *= mr; k5.w *= mr; k8.w *= mr;

    const int oN = hm ? -WW : 0, oS = hp ? WW : 0;    // clamped: addresses stay in-range
    const int dl = (w0 > 0) ? -1 : 0;                 // left scalar (masked if clamped)
    const int dr = (w0 < WW - 4) ? 4 : 3;             // right scalar

    const float* qbase = qin + ((size_t)(b * DD + cg * 8)) * HWN + n0;

    float4 tv[8];
    float4 A4 = make_float4(0.f, 0.f, 0.f, 0.f);
    float4 B4 = make_float4(0.f, 0.f, 0.f, 0.f);
#pragma unroll
    for (int i = 0; i < 8; ++i) {
        const float* qc = qbase + (size_t)i * HWN;
        const float* qn = qc + oN;
        const float* qs = qc + oS;
        float4 Cn = *(const float4*)qn;  float lN = qn[dl], rN = qn[dr];
        float4 C0 = *(const float4*)qc;  float l0 = qc[dl], r0 = qc[dr];
        float4 Cs = *(const float4*)qs;  float lS = qs[dl], rS = qs[dr];

        float4 tt;
        tt.x = k0.x * lN   + k1.x * Cn.x + k2.x * Cn.y
             + k3.x * l0   + k4.x * C0.x + k5.x * C0.y
             + k6.x * lS   + k7.x * Cs.x + k8.x * Cs.y;
        tt.y = k0.y * Cn.x + k1.y * Cn.y + k2.y * Cn.z
             + k3.y * C0.x + k4.y * C0.y + k5.y * C0.z
             + k6.y * Cs.x + k7.y * Cs.y + k8.y * Cs.z;
        tt.z = k0.z * Cn.y + k1.z * Cn.z + k2.z * Cn.w
             + k3.z * C0.y + k4.z * C0.z + k5.z * C0.w
             + k6.z * Cs.y + k7.z * Cs.z + k8.z * Cs.w;
        tt.w = k0.w * Cn.z + k1.w * Cn.w + k2.w * rN
             + k3.w * C0.z + k4.w * C0.w + k5.w * rS * 0.f + k5.w * r0
             + k6.w * Cs.z + k7.w * Cs.w + k8.w * rS;
        tv[i] = tt;

        float e = (float)(cg * 8 + i);
        A4.x += tt.x; A4.y += tt.y; A4.z += tt.z; A4.w += tt.w;
        B4.x += e * tt.x; B4.y += e * tt.y; B4.z += e * tt.z; B4.w += e * tt.w;
    }

    // exclusive prefix + totals across channel-groups (per px component)
    float4 Aex, Bex, T4, E4;
    scan8(A4.x, Aex.x, T4.x, cg, pg); scan8(A4.y, Aex.y, T4.y, cg, pg);
    scan8(A4.z, Aex.z, T4.z, cg, pg); scan8(A4.w, Aex.w, T4.w, cg, pg);
    scan8(B4.x, Bex.x, E4.x, cg, pg); scan8(B4.y, Bex.y, E4.y, cg, pg);
    scan8(B4.z, Bex.z, E4.z, cg, pg); scan8(B4.w, Bex.w, E4.w, cg, pg);

    const float* lg = logits + ((size_t)(b * DD + cg * 8)) * HWN + n0;
    float4 Ar = Aex, Br = Bex;
    float4 S = make_float4(0.f, 0.f, 0.f, 0.f);
#pragma unroll
    for (int i = 0; i < 8; ++i) {
        float4 lgv = *(const float4*)(lg + (size_t)i * HWN);
        float e = (float)(cg * 8 + i);
        Ar.x += tv[i].x; Br.x += e * tv[i].x;
        Ar.y += tv[i].y; Br.y += e * tv[i].y;
        Ar.z += tv[i].z; Br.z += e * tv[i].z;
        Ar.w += tv[i].w; Br.w += e * tv[i].w;
        float vx = lgv.x - (2.f * (e * Ar.x - Br.x) + E4.x - e * T4.x);
        float vy = lgv.y - (2.f * (e * Ar.y - Br.y) + E4.y - e * T4.y);
        float vz = lgv.z - (2.f * (e * Ar.z - Br.z) + E4.z - e * T4.z);
        float vw = lgv.w - (2.f * (e * Ar.w - Br.w) + E4.w - e * T4.w);
        float ux = __expf(vx), uy = __expf(vy), uz = __expf(vz), uw = __expf(vw);
        S.x += ux; S.y += uy; S.z += uz; S.w += uw;
        tv[i].x = ux; tv[i].y = uy; tv[i].z = uz; tv[i].w = uw;
    }
#pragma unroll
    for (int o = 8; o <= 32; o <<= 1) {
        S.x += __shfl_xor(S.x, o); S.y += __shfl_xor(S.y, o);
        S.z += __shfl_xor(S.z, o); S.w += __shfl_xor(S.w, o);
    }
    float4 inv = make_float4(1.f / S.x, 1.f / S.y, 1.f / S.z, 1.f / S.w);

    float* qo = qout + ((size_t)(b * DD + cg * 8)) * HWN + n0;
#pragma unroll
    for (int i = 0; i < 8; ++i) {
        float4 o;
        o.x = tv[i].x * inv.x; o.y = tv[i].y * inv.y;
        o.z = tv[i].z * inv.z; o.w = tv[i].w * inv.w;
        *(float4*)(qo + (size_t)i * HWN) = o;
    }
}

// ---------------------------------------------------------------------------
extern "C" void kernel_launch(void* const* d_in, const int* in_sizes, int n_in,
                              void* d_out, int out_size, void* d_ws, size_t ws_size,
                              hipStream_t stream) {
    const float* color  = (const float*)d_in[0];
    // d_in[1] = feats: unused by the forward pass
    const float* logits = (const float*)d_in[2];
    const float* wsp    = (const float*)d_in[3];

    float* q_out = (float*)d_out;                       // q0, then final q
    float* kaff  = (float*)d_ws;                        // [B,9,HW]  ~13 MB
    float* q1    = (float*)d_ws + (size_t)BB * 9 * HWN; // [B,D,HW]  ~92 MB

    dim3 gridA(HWN / 256, BB);
    dim3 gridQ(HWN / 128, BB);
    affinity_kernel<<<gridA, 256, 0, stream>>>(color, wsp, kaff);
    softmax0_kernel<<<gridQ, 256, 0, stream>>>(logits, q_out);
    crf_iter_kernel<<<gridQ, 256, 0, stream>>>(q_out, logits, kaff, q1);
    crf_iter_kernel<<<gridQ, 256, 0, stream>>>(q1, logits, kaff, q_out);
}